// Round 3
// baseline (138.831 us; speedup 1.0000x reference)
//
#include <hip/hip_runtime.h>
#include <hip/hip_bf16.h>
#include <math.h>

#define B 384
#define C 512
#define NPAIR (B * B)          // 147456
#define NOFF  (B * (B - 1))    // 147072

#define T16  24   // 16x16 tiles per dim in gram
#define UP16 300  // upper-incl-diag tile count (24*25/2)
#define T64  6    // 64x64 tiles per dim in angle
#define UP64 21   // 6*7/2
#define NANG (UP64 * 48)  // 1008 angle blocks

// ws layout (floats) — every slot written before read within one launch; no zero-init needed
// (the completion counter CNT_OFF is zeroed by k_gram, which is stream-ordered before k_angle).
#define HARD_OFF 0            // 384: per-row CE
#define DSUM_OFF 384          // 600: per-gram-wave weighted d-sums (s: [0,300), t: [300,600))
#define ANG_OFF  984          // 1008: per-angle-block huber partials
#define DIST_OFF 1992         // 21: per-(y==0)-angle-block dist-huber partials
#define SQS_OFF  2016         // 384
#define SQT_OFF  2400         // 384
#define CNT_OFF  2784         // 1: k_angle completion ticket counter
#define PS_OFF   2816         // 147456 (16B-aligned)
#define PT_OFF   (PS_OFF + NPAIR)
// total = PT_OFF + NPAIR = 297728 floats ≈ 1.14 MB

typedef __attribute__((ext_vector_type(8))) short short8;
typedef __attribute__((ext_vector_type(4))) float floatx4;

__device__ __forceinline__ float blk_sum(float v, float* s4, int t) {
#pragma unroll
  for (int off = 32; off > 0; off >>= 1) v += __shfl_down(v, off, 64);
  if ((t & 63) == 0) s4[t >> 6] = v;
  __syncthreads();
  float r = s4[0] + s4[1] + s4[2] + s4[3];
  __syncthreads();
  return r;
}

__device__ __forceinline__ short bfc(float x) {
  __hip_bfloat16 h = __float2bfloat16(x);
  return __builtin_bit_cast(short, h);
}

__device__ __forceinline__ short8 load_frag(const float* p) {
  float4 lo = *(const float4*)p;
  float4 hi = *(const float4*)(p + 4);
  short8 v;
  v[0] = bfc(lo.x); v[1] = bfc(lo.y); v[2] = bfc(lo.z); v[3] = bfc(lo.w);
  v[4] = bfc(hi.x); v[5] = bfc(hi.y); v[6] = bfc(hi.z); v[7] = bfc(hi.w);
  return v;
}

// K1: wave-per-row sq norms (s,t) + per-row CE. 96 blocks x 4 waves, shfl-only reductions.
__global__ __launch_bounds__(256) void k_row(const float* __restrict__ fs,
                                             const float* __restrict__ ft,
                                             const int* __restrict__ lab,
                                             float* __restrict__ ws) {
  int t = threadIdx.x;
  int wv = t >> 6, lane = t & 63;
  int r = blockIdx.x * 4 + wv;
  const float* xs = fs + r * C;
  const float* xt = ft + r * C;
  float4 a0 = *(const float4*)&xs[lane * 8];
  float4 a1 = *(const float4*)&xs[lane * 8 + 4];
  float4 b0 = *(const float4*)&xt[lane * 8];
  float4 b1 = *(const float4*)&xt[lane * 8 + 4];
  float m = fmaxf(fmaxf(fmaxf(a0.x, a0.y), fmaxf(a0.z, a0.w)),
                  fmaxf(fmaxf(a1.x, a1.y), fmaxf(a1.z, a1.w)));
#pragma unroll
  for (int off = 32; off > 0; off >>= 1) m = fmaxf(m, __shfl_down(m, off, 64));
  m = __shfl(m, 0, 64);
  float es = expf(a0.x - m) + expf(a0.y - m) + expf(a0.z - m) + expf(a0.w - m) +
             expf(a1.x - m) + expf(a1.y - m) + expf(a1.z - m) + expf(a1.w - m);
  float ss = a0.x * a0.x + a0.y * a0.y + a0.z * a0.z + a0.w * a0.w +
             a1.x * a1.x + a1.y * a1.y + a1.z * a1.z + a1.w * a1.w;
  float st = b0.x * b0.x + b0.y * b0.y + b0.z * b0.z + b0.w * b0.w +
             b1.x * b1.x + b1.y * b1.y + b1.z * b1.z + b1.w * b1.w;
#pragma unroll
  for (int off = 32; off > 0; off >>= 1) {
    es += __shfl_down(es, off, 64);
    ss += __shfl_down(ss, off, 64);
    st += __shfl_down(st, off, 64);
  }
  if (lane == 0) {
    ws[SQS_OFF + r] = ss;
    ws[SQT_OFF + r] = st;
    ws[HARD_OFF + r] = m + logf(es) - xs[lab[r]];
  }
}

// K2: P = F F^T via bf16 MFMA 16x16x32, one 16x16 tile per wave, upper tiles only,
// symmetric store; epilogue accumulates weighted off-diag distance sum per wave slot.
// Also zeroes the k_angle completion counter (stream-ordered before k_angle).
__global__ __launch_bounds__(256, 4) void k_gram(const float* __restrict__ fs,
                                                 const float* __restrict__ ft,
                                                 float* __restrict__ ws) {
  int t = threadIdx.x;
  if (blockIdx.x == 0 && t == 0) ((unsigned int*)ws)[CNT_OFF] = 0u;
  int w = t >> 6, lane = t & 63;
  int g = blockIdx.x * 4 + w;        // [0, 600)
  int tensor = (g >= UP16) ? 1 : 0;
  int uu = g - tensor * UP16;
  int ti = 0;
  while (uu >= T16 - ti) { uu -= T16 - ti; ++ti; }
  int tj = ti + uu;
  const float* F = tensor ? ft : fs;
  const float* sq = ws + (tensor ? SQT_OFF : SQS_OFF);
  float* P = ws + (tensor ? PT_OFF : PS_OFF);
  int i0 = ti * 16, j0 = tj * 16;
  int r = lane & 15, q = lane >> 4;
  // A[m=lane&15][k=quad*8+j], B[k=quad*8+j][n=lane&15] (m89-verified mapping)
  const float* arow = F + (i0 + r) * C + q * 8;
  const float* brow = F + (j0 + r) * C + q * 8;
  floatx4 acc = {0.f, 0.f, 0.f, 0.f};
#pragma unroll
  for (int ks = 0; ks < 16; ++ks) {
    short8 a = load_frag(arow + ks * 32);
    short8 b = load_frag(brow + ks * 32);
    acc = __builtin_amdgcn_mfma_f32_16x16x32_bf16(a, b, acc, 0, 0, 0);
  }
  // C/D layout: col = lane&15, row = quad*4 + reg
  int col = lane & 15;
  int j = j0 + col;
  float sqj = sq[j];
  float dsum = 0.f;
#pragma unroll
  for (int reg = 0; reg < 4; ++reg) {
    int i = i0 + q * 4 + reg;
    float p = acc[reg];
    P[i * B + j] = p;
    P[j * B + i] = p;   // symmetric mirror (diag tile: identical value, benign)
    float d2 = sq[i] + sqj - 2.f * p;
    float d = sqrtf(fmaxf(d2, 1e-12f));
    float wgt = (ti < tj) ? 2.f : ((i < j) ? 2.f : 0.f);
    dsum = fmaf(wgt, d, dsum);
  }
#pragma unroll
  for (int off = 32; off > 0; off >>= 1) dsum += __shfl_down(dsum, off, 64);
  if (lane == 0) ws[DSUM_OFF + g] = dsum;
}

// K3: angle-huber over upper-triangle (i,j) tiles via Gram identity; dist-huber fused
// into y==0 blocks; final combine fused into the last-finishing block (ticket pattern).
#define BCH 8
#define ANGLE_BODY(MASKED)                                                   \
  for (int b = 0; b < BCH; ++b) {                                            \
    float uis[4], qis[4], uit[4], qit[4], ujs[4], qjs[4], ujt[4], qjt[4];    \
    float4 v;                                                                \
    v = *(const float4*)&sI[b][0][ty * 4];                                   \
    uis[0] = v.x; uis[1] = v.y; uis[2] = v.z; uis[3] = v.w;                  \
    v = *(const float4*)&sI[b][1][ty * 4];                                   \
    qis[0] = v.x; qis[1] = v.y; qis[2] = v.z; qis[3] = v.w;                  \
    v = *(const float4*)&sI[b][2][ty * 4];                                   \
    uit[0] = v.x; uit[1] = v.y; uit[2] = v.z; uit[3] = v.w;                  \
    v = *(const float4*)&sI[b][3][ty * 4];                                   \
    qit[0] = v.x; qit[1] = v.y; qit[2] = v.z; qit[3] = v.w;                  \
    v = *(const float4*)&sJ[b][0][tx * 4];                                   \
    ujs[0] = v.x; ujs[1] = v.y; ujs[2] = v.z; ujs[3] = v.w;                  \
    v = *(const float4*)&sJ[b][1][tx * 4];                                   \
    qjs[0] = v.x; qjs[1] = v.y; qjs[2] = v.z; qjs[3] = v.w;                  \
    v = *(const float4*)&sJ[b][2][tx * 4];                                   \
    ujt[0] = v.x; ujt[1] = v.y; ujt[2] = v.z; ujt[3] = v.w;                  \
    v = *(const float4*)&sJ[b][3][tx * 4];                                   \
    qjt[0] = v.x; qjt[1] = v.y; qjt[2] = v.z; qjt[3] = v.w;                  \
    _Pragma("unroll")                                                        \
    for (int r = 0; r < 4; ++r) {                                            \
      _Pragma("unroll")                                                      \
      for (int c = 0; c < 4; ++c) {                                          \
        float f1s = fmaf(uis[r], ps[r][c], -qis[r]);                         \
        float gs = fmaf(ujs[c], f1s, -(uis[r] * qjs[c]));                    \
        float f1t = fmaf(uit[r], pt[r][c], -qit[r]);                         \
        float gt = fmaf(ujt[c], f1t, -(uit[r] * qjt[c]));                    \
        float a = fabsf(gs - gt);                                            \
        if (MASKED) a = (ty * 4 + r < tx * 4 + c) ? a : 0.f;                 \
        float mm = fminf(a, 1.f);                                            \
        acc = fmaf(mm, fmaf(-0.5f, mm, a), acc);                             \
      }                                                                      \
    }                                                                        \
  }

__global__ __launch_bounds__(256, 4) void k_angle(float* __restrict__ ws,
                                                  float* __restrict__ out) {
  const float* Ps = ws + PS_OFF;
  const float* Pt = ws + PT_OFF;
  const float* sqs = ws + SQS_OFF;
  const float* sqt = ws + SQT_OFF;
  int uu = blockIdx.x;
  int ti = 0;
  while (uu >= T64 - ti) { uu -= T64 - ti; ++ti; }
  int tj = ti + uu;
  int i0 = ti * 64, j0 = tj * 64;
  bool diag = (ti == tj);
  int b0 = blockIdx.y * BCH;
  int t = threadIdx.x;
  int ty = t >> 4, tx = t & 15;

  __shared__ float sI[BCH][4][64];  // planes: us, qs, ut, qt
  __shared__ float sJ[BCH][4][64];
  __shared__ float s4[4];
  __shared__ unsigned int s_ticket;

  float ps[4][4], pt[4][4];
#pragma unroll
  for (int r = 0; r < 4; ++r) {
    float4 v = *(const float4*)&Ps[(i0 + ty * 4 + r) * B + j0 + tx * 4];
    ps[r][0] = v.x; ps[r][1] = v.y; ps[r][2] = v.z; ps[r][3] = v.w;
    v = *(const float4*)&Pt[(i0 + ty * 4 + r) * B + j0 + tx * 4];
    pt[r][0] = v.x; pt[r][1] = v.y; pt[r][2] = v.z; pt[r][3] = v.w;
  }

  for (int idx = t; idx < BCH * 128; idx += 256) {
    int b = idx >> 7, p = idx & 127;
    int bb = b0 + b;
    int col = (p < 64) ? (i0 + p) : (j0 + p - 64);
    float pvs = Ps[bb * B + col];
    float pvt = Pt[bb * B + col];
    float pbbs = Ps[bb * B + bb];
    float pbbt = Pt[bb * B + bb];
    float d2s = sqs[bb] + sqs[col] - 2.f * pvs;
    float d2t = sqt[bb] + sqt[col] - 2.f * pvt;
    float us = (col == bb) ? 0.f : rsqrtf(fmaxf(d2s, 1e-24f));
    float ut = (col == bb) ? 0.f : rsqrtf(fmaxf(d2t, 1e-24f));
    float qs = us * (pvs - 0.5f * pbbs);
    float qt = ut * (pvt - 0.5f * pbbt);
    float* dst = (p < 64) ? &sI[b][0][p] : &sJ[b][0][p - 64];
    dst[0] = us; dst[64] = qs; dst[128] = ut; dst[192] = qt;
  }
  __syncthreads();

  float acc = 0.f;
  if (diag) { ANGLE_BODY(true) } else { ANGLE_BODY(false) }

  float asum = blk_sum(acc, s4, t);
  if (t == 0) ws[ANG_OFF + blockIdx.y * UP64 + blockIdx.x] = asum;

  if (blockIdx.y == 0) {  // fused dist-huber over this (i,j) tile
    float ssum = 0.f, tsum = 0.f;
    for (int i = t; i < UP16; i += 256) ssum += ws[DSUM_OFF + i];
    for (int i = t; i < UP16; i += 256) tsum += ws[DSUM_OFF + UP16 + i];
    ssum = blk_sum(ssum, s4, t);
    tsum = blk_sum(tsum, s4, t);
    float inv_ms = (float)NOFF / ssum;
    float inv_mt = (float)NOFF / tsum;
    float sqsi[4], sqti[4], sqsj[4], sqtj[4];
#pragma unroll
    for (int r = 0; r < 4; ++r) {
      sqsi[r] = sqs[i0 + ty * 4 + r];
      sqti[r] = sqt[i0 + ty * 4 + r];
      sqsj[r] = sqs[j0 + tx * 4 + r];
      sqtj[r] = sqt[j0 + tx * 4 + r];
    }
    float dacc = 0.f;
#pragma unroll
    for (int r = 0; r < 4; ++r)
#pragma unroll
      for (int c = 0; c < 4; ++c) {
        float d2s = sqsi[r] + sqsj[c] - 2.f * ps[r][c];
        float d2t = sqti[r] + sqtj[c] - 2.f * pt[r][c];
        float dsv = sqrtf(fmaxf(d2s, 1e-12f)) * inv_ms;
        float dtv = sqrtf(fmaxf(d2t, 1e-12f)) * inv_mt;
        float a = fabsf(dsv - dtv);
        if (diag) a = (ty * 4 + r < tx * 4 + c) ? a : 0.f;
        float mm = fminf(a, 1.f);
        dacc = fmaf(mm, fmaf(-0.5f, mm, a), dacc);
      }
    float dsum2 = blk_sum(dacc, s4, t);
    if (t == 0) ws[DIST_OFF + blockIdx.x] = dsum2;
  }

  // ---- fused final combine: last block to finish does the tiny reduction ----
  __threadfence();  // release our partial stores device-wide
  if (t == 0) s_ticket = atomicAdd((unsigned int*)ws + CNT_OFF, 1u);
  __syncthreads();
  if (s_ticket == NANG - 1) {
    __threadfence();  // acquire all other blocks' partials
    float h = 0.f, aa = 0.f, dd = 0.f;
    for (int i = t; i < B; i += 256) h += ws[HARD_OFF + i];
    for (int i = t; i < NANG; i += 256) aa += ws[ANG_OFF + i];
    for (int i = t; i < UP64; i += 256) dd += ws[DIST_OFF + i];
    h = blk_sum(h, s4, t);
    aa = blk_sum(aa, s4, t);
    dd = blk_sum(dd, s4, t);
    if (t == 0)
      out[0] = h * (1.f / (float)B) + 2.f * dd * (1.f / (float)NPAIR) +
               2.f * aa * (1.f / 56623104.f);  // 384^3
  }
}

extern "C" void kernel_launch(void* const* d_in, const int* in_sizes, int n_in,
                              void* d_out, int out_size, void* d_ws, size_t ws_size,
                              hipStream_t stream) {
  (void)in_sizes; (void)n_in; (void)out_size; (void)ws_size;
  const float* fs = (const float*)d_in[0];
  const float* ft = (const float*)d_in[1];
  const int* lab = (const int*)d_in[2];
  float* ws = (float*)d_ws;
  float* out = (float*)d_out;

  k_row<<<96, 256, 0, stream>>>(fs, ft, lab, ws);    // 384 waves, one row each
  k_gram<<<150, 256, 0, stream>>>(fs, ft, ws);       // 600 waves = 600 upper 16x16 tiles x2 tensors
  k_angle<<<dim3(UP64, 48), 256, 0, stream>>>(ws, out);  // 21 tiles x 48 b-groups + fused final
}

// Round 4
// 104.419 us; speedup vs baseline: 1.3296x; 1.3296x over previous
//
#include <hip/hip_runtime.h>
#include <hip/hip_bf16.h>
#include <math.h>

#define B 384
#define C 512
#define NPAIR (B * B)          // 147456
#define NOFF  (B * (B - 1))    // 147072

#define T16  24   // 16x16 tiles per dim in gram
#define UP16 300  // upper-incl-diag tile count (24*25/2)
#define T64  6    // 64x64 tiles per dim in angle
#define UP64 21   // 6*7/2
#define NANG (UP64 * 48)  // 1008 angle blocks

// ws layout (floats). Cross-dispatch data (HARD/SQ/P, and the zeroed ACC slots) are
// plain stores — visible to the next dispatch via kernel-boundary flush. All
// *intra*-k_angle cross-block communication is atomics-only (device coherence
// point), so NO fences anywhere (round-3's __threadfence caused L2 wb/inv storms).
#define HARD_OFF 0            // 384: per-row CE
#define SQS_OFF  384          // 384
#define SQT_OFF  768          // 384
#define ACC_OFF  1152         // [0]=DS, [1]=DT, [2]=ANG, [3]=DIST (f32); [4]=CNT1, [5]=CNT2 (u32)
#define PS_OFF   1216         // 147456 (16B-aligned: 1216*4=4864)
#define PT_OFF   (PS_OFF + NPAIR)

typedef __attribute__((ext_vector_type(8))) short short8;
typedef __attribute__((ext_vector_type(4))) float floatx4;

__device__ __forceinline__ float blk_sum(float v, float* s4, int t) {
#pragma unroll
  for (int off = 32; off > 0; off >>= 1) v += __shfl_down(v, off, 64);
  if ((t & 63) == 0) s4[t >> 6] = v;
  __syncthreads();
  float r = s4[0] + s4[1] + s4[2] + s4[3];
  __syncthreads();
  return r;
}

__device__ __forceinline__ short bfc(float x) {
  __hip_bfloat16 h = __float2bfloat16(x);
  return __builtin_bit_cast(short, h);
}

__device__ __forceinline__ short8 load_frag(const float* p) {
  float4 lo = *(const float4*)p;
  float4 hi = *(const float4*)(p + 4);
  short8 v;
  v[0] = bfc(lo.x); v[1] = bfc(lo.y); v[2] = bfc(lo.z); v[3] = bfc(lo.w);
  v[4] = bfc(hi.x); v[5] = bfc(hi.y); v[6] = bfc(hi.z); v[7] = bfc(hi.w);
  return v;
}

// K_A: blocks [0,96) = wave-per-row CE + sq norms; blocks [96,246) = gram tiles.
// Block 0 also zeroes the atomic accumulator slots for k_angle.
__global__ __launch_bounds__(256, 4) void k_pre(const float* __restrict__ fs,
                                                const float* __restrict__ ft,
                                                const int* __restrict__ lab,
                                                float* __restrict__ ws) {
  int t = threadIdx.x;
  if (blockIdx.x < 96) {
    if (blockIdx.x == 0 && t < 8) ((unsigned int*)ws)[ACC_OFF + t] = 0u;
    int wv = t >> 6, lane = t & 63;
    int r = blockIdx.x * 4 + wv;
    const float* xs = fs + r * C;
    const float* xt = ft + r * C;
    float4 a0 = *(const float4*)&xs[lane * 8];
    float4 a1 = *(const float4*)&xs[lane * 8 + 4];
    float4 b0 = *(const float4*)&xt[lane * 8];
    float4 b1 = *(const float4*)&xt[lane * 8 + 4];
    float m = fmaxf(fmaxf(fmaxf(a0.x, a0.y), fmaxf(a0.z, a0.w)),
                    fmaxf(fmaxf(a1.x, a1.y), fmaxf(a1.z, a1.w)));
#pragma unroll
    for (int off = 32; off > 0; off >>= 1) m = fmaxf(m, __shfl_down(m, off, 64));
    m = __shfl(m, 0, 64);
    float es = expf(a0.x - m) + expf(a0.y - m) + expf(a0.z - m) + expf(a0.w - m) +
               expf(a1.x - m) + expf(a1.y - m) + expf(a1.z - m) + expf(a1.w - m);
    float ss = a0.x * a0.x + a0.y * a0.y + a0.z * a0.z + a0.w * a0.w +
               a1.x * a1.x + a1.y * a1.y + a1.z * a1.z + a1.w * a1.w;
    float st = b0.x * b0.x + b0.y * b0.y + b0.z * b0.z + b0.w * b0.w +
               b1.x * b1.x + b1.y * b1.y + b1.z * b1.z + b1.w * b1.w;
#pragma unroll
    for (int off = 32; off > 0; off >>= 1) {
      es += __shfl_down(es, off, 64);
      ss += __shfl_down(ss, off, 64);
      st += __shfl_down(st, off, 64);
    }
    if (lane == 0) {
      ws[SQS_OFF + r] = ss;
      ws[SQT_OFF + r] = st;
      ws[HARD_OFF + r] = m + logf(es) - xs[lab[r]];
    }
  } else {
    int w = t >> 6, lane = t & 63;
    int g = (blockIdx.x - 96) * 4 + w;   // [0, 600)
    int tensor = (g >= UP16) ? 1 : 0;
    int uu = g - tensor * UP16;
    int ti = 0;
    while (uu >= T16 - ti) { uu -= T16 - ti; ++ti; }
    int tj = ti + uu;
    const float* F = tensor ? ft : fs;
    float* P = ws + (tensor ? PT_OFF : PS_OFF);
    int i0 = ti * 16, j0 = tj * 16;
    int r = lane & 15, q = lane >> 4;
    // A[m=lane&15][k=quad*8+j], B[k=quad*8+j][n=lane&15] (m89-verified mapping)
    const float* arow = F + (i0 + r) * C + q * 8;
    const float* brow = F + (j0 + r) * C + q * 8;
    floatx4 acc = {0.f, 0.f, 0.f, 0.f};
#pragma unroll
    for (int ks = 0; ks < 16; ++ks) {
      short8 a = load_frag(arow + ks * 32);
      short8 b = load_frag(brow + ks * 32);
      acc = __builtin_amdgcn_mfma_f32_16x16x32_bf16(a, b, acc, 0, 0, 0);
    }
    // C/D layout: col = lane&15, row = quad*4 + reg
    int j = j0 + (lane & 15);
#pragma unroll
    for (int reg = 0; reg < 4; ++reg) {
      int i = i0 + q * 4 + reg;
      float p = acc[reg];
      P[i * B + j] = p;
      P[j * B + i] = p;   // symmetric mirror (diag tile: identical value, benign)
    }
  }
}

// K_B: angle-huber over upper-triangle 64x64 (i,j) tiles via Gram identity.
// y==0 blocks additionally: tile d-sums -> atomic acc -> mini-ticket -> (after angle
// body) spin, then dist-huber. Last-finishing block does the final combine.
#define BCH 8
#define ANGLE_BODY(MASKED)                                                   \
  for (int b = 0; b < BCH; ++b) {                                            \
    float uis[4], qis[4], uit[4], qit[4], ujs[4], qjs[4], ujt[4], qjt[4];    \
    float4 v;                                                                \
    v = *(const float4*)&sI[b][0][ty * 4];                                   \
    uis[0] = v.x; uis[1] = v.y; uis[2] = v.z; uis[3] = v.w;                  \
    v = *(const float4*)&sI[b][1][ty * 4];                                   \
    qis[0] = v.x; qis[1] = v.y; qis[2] = v.z; qis[3] = v.w;                  \
    v = *(const float4*)&sI[b][2][ty * 4];                                   \
    uit[0] = v.x; uit[1] = v.y; uit[2] = v.z; uit[3] = v.w;                  \
    v = *(const float4*)&sI[b][3][ty * 4];                                   \
    qit[0] = v.x; qit[1] = v.y; qit[2] = v.z; qit[3] = v.w;                  \
    v = *(const float4*)&sJ[b][0][tx * 4];                                   \
    ujs[0] = v.x; ujs[1] = v.y; ujs[2] = v.z; ujs[3] = v.w;                  \
    v = *(const float4*)&sJ[b][1][tx * 4];                                   \
    qjs[0] = v.x; qjs[1] = v.y; qjs[2] = v.z; qjs[3] = v.w;                  \
    v = *(const float4*)&sJ[b][2][tx * 4];                                   \
    ujt[0] = v.x; ujt[1] = v.y; ujt[2] = v.z; ujt[3] = v.w;                  \
    v = *(const float4*)&sJ[b][3][tx * 4];                                   \
    qjt[0] = v.x; qjt[1] = v.y; qjt[2] = v.z; qjt[3] = v.w;                  \
    _Pragma("unroll")                                                        \
    for (int r = 0; r < 4; ++r) {                                            \
      _Pragma("unroll")                                                      \
      for (int c = 0; c < 4; ++c) {                                          \
        float f1s = fmaf(uis[r], ps[r][c], -qis[r]);                         \
        float gs = fmaf(ujs[c], f1s, -(uis[r] * qjs[c]));                    \
        float f1t = fmaf(uit[r], pt[r][c], -qit[r]);                         \
        float gt = fmaf(ujt[c], f1t, -(uit[r] * qjt[c]));                    \
        float a = fabsf(gs - gt);                                            \
        if (MASKED) a = (ty * 4 + r < tx * 4 + c) ? a : 0.f;                 \
        float mm = fminf(a, 1.f);                                            \
        acc = fmaf(mm, fmaf(-0.5f, mm, a), acc);                             \
      }                                                                      \
    }                                                                        \
  }

__global__ __launch_bounds__(256, 4) void k_angle(float* __restrict__ ws,
                                                  float* __restrict__ out) {
  const float* Ps = ws + PS_OFF;
  const float* Pt = ws + PT_OFF;
  const float* sqs = ws + SQS_OFF;
  const float* sqt = ws + SQT_OFF;
  float* acc_ws = ws + ACC_OFF;                    // [0]DS [1]DT [2]ANG [3]DIST
  unsigned int* cnt_ws = (unsigned int*)(ws + ACC_OFF);  // [4]CNT1 [5]CNT2

  int uu = blockIdx.x;
  int ti = 0;
  while (uu >= T64 - ti) { uu -= T64 - ti; ++ti; }
  int tj = ti + uu;
  int i0 = ti * 64, j0 = tj * 64;
  bool diag = (ti == tj);
  int b0 = blockIdx.y * BCH;
  int t = threadIdx.x;
  int ty = t >> 4, tx = t & 15;

  __shared__ float sI[BCH][4][64];  // planes: us, qs, ut, qt
  __shared__ float sJ[BCH][4][64];
  __shared__ float s4[4];
  __shared__ float sbc[2];
  __shared__ unsigned int stk;

  float ps[4][4], pt[4][4];
#pragma unroll
  for (int r = 0; r < 4; ++r) {
    float4 v = *(const float4*)&Ps[(i0 + ty * 4 + r) * B + j0 + tx * 4];
    ps[r][0] = v.x; ps[r][1] = v.y; ps[r][2] = v.z; ps[r][3] = v.w;
    v = *(const float4*)&Pt[(i0 + ty * 4 + r) * B + j0 + tx * 4];
    pt[r][0] = v.x; pt[r][1] = v.y; pt[r][2] = v.z; pt[r][3] = v.w;
  }

  float sqsi[4], sqti[4], sqsj[4], sqtj[4];
  unsigned int dep_extra = 0;

  if (blockIdx.y == 0) {
    // tile d-sums (strict upper half counted once; full sum = 2x)
#pragma unroll
    for (int r = 0; r < 4; ++r) {
      sqsi[r] = sqs[i0 + ty * 4 + r];
      sqti[r] = sqt[i0 + ty * 4 + r];
      sqsj[r] = sqs[j0 + tx * 4 + r];
      sqtj[r] = sqt[j0 + tx * 4 + r];
    }
    float ssum = 0.f, tsum = 0.f;
#pragma unroll
    for (int r = 0; r < 4; ++r)
#pragma unroll
      for (int c = 0; c < 4; ++c) {
        float wgt = diag ? ((ty * 4 + r < tx * 4 + c) ? 1.f : 0.f) : 1.f;
        float d2s = sqsi[r] + sqsj[c] - 2.f * ps[r][c];
        float d2t = sqti[r] + sqtj[c] - 2.f * pt[r][c];
        ssum = fmaf(wgt, sqrtf(fmaxf(d2s, 1e-12f)), ssum);
        tsum = fmaf(wgt, sqrtf(fmaxf(d2t, 1e-12f)), tsum);
      }
    ssum = blk_sum(ssum, s4, t);
    tsum = blk_sum(tsum, s4, t);
    if (t == 0) {
      float oS = atomicAdd(&acc_ws[0], ssum);
      float oT = atomicAdd(&acc_ws[1], tsum);
      unsigned int dep = __float_as_uint(oS) ^ __float_as_uint(oT);
      asm volatile("" : : "v"(dep) : "memory");  // order adds before ticket
      atomicAdd(&cnt_ws[4], 1u);
    }
  }

  for (int idx = t; idx < BCH * 128; idx += 256) {
    int b = idx >> 7, p = idx & 127;
    int bb = b0 + b;
    int col = (p < 64) ? (i0 + p) : (j0 + p - 64);
    float pvs = Ps[bb * B + col];
    float pvt = Pt[bb * B + col];
    float pbbs = Ps[bb * B + bb];
    float pbbt = Pt[bb * B + bb];
    float d2s = sqs[bb] + sqs[col] - 2.f * pvs;
    float d2t = sqt[bb] + sqt[col] - 2.f * pvt;
    float us = (col == bb) ? 0.f : rsqrtf(fmaxf(d2s, 1e-24f));
    float ut = (col == bb) ? 0.f : rsqrtf(fmaxf(d2t, 1e-24f));
    float qs = us * (pvs - 0.5f * pbbs);
    float qt = ut * (pvt - 0.5f * pbbt);
    float* dst = (p < 64) ? &sI[b][0][p] : &sJ[b][0][p - 64];
    dst[0] = us; dst[64] = qs; dst[128] = ut; dst[192] = qt;
  }
  __syncthreads();

  float acc = 0.f;
  if (diag) { ANGLE_BODY(true) } else { ANGLE_BODY(false) }
  float asum = blk_sum(acc, s4, t);

  if (blockIdx.y == 0) {
    // spin on mini-ticket (each of the 21 blocks contributed before any spins)
    if (t == 0) {
      unsigned int c;
      do {
        c = __hip_atomic_load(&cnt_ws[4], __ATOMIC_RELAXED, __HIP_MEMORY_SCOPE_AGENT);
      } while (c < UP64);
      sbc[0] = __hip_atomic_load(&acc_ws[0], __ATOMIC_RELAXED, __HIP_MEMORY_SCOPE_AGENT);
      sbc[1] = __hip_atomic_load(&acc_ws[1], __ATOMIC_RELAXED, __HIP_MEMORY_SCOPE_AGENT);
    }
    __syncthreads();
    float inv_ms = (float)NOFF / (2.f * sbc[0]);
    float inv_mt = (float)NOFF / (2.f * sbc[1]);
    float dacc = 0.f;
#pragma unroll
    for (int r = 0; r < 4; ++r)
#pragma unroll
      for (int c = 0; c < 4; ++c) {
        float d2s = sqsi[r] + sqsj[c] - 2.f * ps[r][c];
        float d2t = sqti[r] + sqtj[c] - 2.f * pt[r][c];
        float dsv = sqrtf(fmaxf(d2s, 1e-12f)) * inv_ms;
        float dtv = sqrtf(fmaxf(d2t, 1e-12f)) * inv_mt;
        float a = fabsf(dsv - dtv);
        if (diag) a = (ty * 4 + r < tx * 4 + c) ? a : 0.f;
        float mm = fminf(a, 1.f);
        dacc = fmaf(mm, fmaf(-0.5f, mm, a), dacc);
      }
    float dsum2 = blk_sum(dacc, s4, t);
    if (t == 0) {
      float oD = atomicAdd(&acc_ws[3], dsum2);
      dep_extra = __float_as_uint(oD);
    }
  }

  // fence-free final ticket: atomic partials -> hw-ordered ticket -> last block combines
  if (t == 0) {
    float oA = atomicAdd(&acc_ws[2], asum);
    unsigned int dep = __float_as_uint(oA) ^ dep_extra;
    asm volatile("" : : "v"(dep) : "memory");
    stk = atomicAdd(&cnt_ws[5], 1u);
  }
  __syncthreads();
  if (stk == NANG - 1) {
    float h = 0.f;
    for (int i = t; i < B; i += 256) h += ws[HARD_OFF + i];  // prior dispatch: plain ok
    h = blk_sum(h, s4, t);
    if (t == 0) {
      float A = __hip_atomic_load(&acc_ws[2], __ATOMIC_RELAXED, __HIP_MEMORY_SCOPE_AGENT);
      float D = __hip_atomic_load(&acc_ws[3], __ATOMIC_RELAXED, __HIP_MEMORY_SCOPE_AGENT);
      out[0] = h * (1.f / (float)B) + 2.f * D * (1.f / (float)NPAIR) +
               2.f * A * (1.f / 56623104.f);  // 384^3
    }
  }
}

extern "C" void kernel_launch(void* const* d_in, const int* in_sizes, int n_in,
                              void* d_out, int out_size, void* d_ws, size_t ws_size,
                              hipStream_t stream) {
  (void)in_sizes; (void)n_in; (void)out_size; (void)ws_size;
  const float* fs = (const float*)d_in[0];
  const float* ft = (const float*)d_in[1];
  const int* lab = (const int*)d_in[2];
  float* ws = (float*)d_ws;
  float* out = (float*)d_out;

  k_pre<<<246, 256, 0, stream>>>(fs, ft, lab, ws);        // 96 row blocks + 150 gram blocks
  k_angle<<<dim3(UP64, 48), 256, 0, stream>>>(ws, out);   // 21 tiles x 48 b-groups + fused final
}

// Round 5
// 86.095 us; speedup vs baseline: 1.6125x; 1.2128x over previous
//
#include <hip/hip_runtime.h>
#include <hip/hip_bf16.h>
#include <math.h>

#define B 384
#define C 512
#define NPAIR (B * B)          // 147456
#define NOFF  (B * (B - 1))    // 147072

#define T16  24   // 16x16 tiles per dim in gram
#define UP16 300  // upper-incl-diag tile count (24*25/2)
#define T64  6    // 64x64 tiles per dim in angle
#define UP64 21   // 6*7/2
#define NBG  32   // b-groups in angle (384 / BCH)
#define NANG (UP64 * NBG)  // 672 angle blocks

// ws layout (floats). ALL cross-block data crosses a dispatch boundary as plain
// stores to distinct addresses (kernel-boundary flush makes them visible).
// Zero atomics / fences / spins — rounds 3-4 showed both fusion mechanisms
// (fences: L2 wb/inv storms; same-line atomics: coherence-point serialization)
// cost more than the ~4 us a separate reducer dispatch costs.
#define HARD_OFF 0            // 384: per-row CE
#define DSUM_OFF 384          // 600: per-gram-wave weighted d-sums (s: [0,300), t: [300,600))
#define ANG_OFF  984          // 672: per-angle-block huber partials
#define DIST_OFF 1656         // 21: per-(y==0)-angle-block dist-huber partials
#define SQS_OFF  1680         // 384
#define SQT_OFF  2064         // 384
#define PS_OFF   2448         // 147456 (2448*4 = 9792, 16B-aligned)
#define PT_OFF   (PS_OFF + NPAIR)

typedef __attribute__((ext_vector_type(8))) short short8;
typedef __attribute__((ext_vector_type(4))) float floatx4;

__device__ __forceinline__ float blk_sum(float v, float* s4, int t) {
#pragma unroll
  for (int off = 32; off > 0; off >>= 1) v += __shfl_down(v, off, 64);
  if ((t & 63) == 0) s4[t >> 6] = v;
  __syncthreads();
  float r = s4[0] + s4[1] + s4[2] + s4[3];
  __syncthreads();
  return r;
}

__device__ __forceinline__ short bfc(float x) {
  __hip_bfloat16 h = __float2bfloat16(x);
  return __builtin_bit_cast(short, h);
}

// K_A: blocks [0,96) = wave-per-row CE + sq norms; blocks [96,246) = gram tiles
// with fused weighted-distance-sum epilogue (row norms recomputed in-register).
__global__ __launch_bounds__(256, 4) void k_pre(const float* __restrict__ fs,
                                                const float* __restrict__ ft,
                                                const int* __restrict__ lab,
                                                float* __restrict__ ws) {
  int t = threadIdx.x;
  if (blockIdx.x < 96) {
    int wv = t >> 6, lane = t & 63;
    int r = blockIdx.x * 4 + wv;
    const float* xs = fs + r * C;
    const float* xt = ft + r * C;
    float4 a0 = *(const float4*)&xs[lane * 8];
    float4 a1 = *(const float4*)&xs[lane * 8 + 4];
    float4 b0 = *(const float4*)&xt[lane * 8];
    float4 b1 = *(const float4*)&xt[lane * 8 + 4];
    float m = fmaxf(fmaxf(fmaxf(a0.x, a0.y), fmaxf(a0.z, a0.w)),
                    fmaxf(fmaxf(a1.x, a1.y), fmaxf(a1.z, a1.w)));
#pragma unroll
    for (int off = 32; off > 0; off >>= 1) m = fmaxf(m, __shfl_down(m, off, 64));
    m = __shfl(m, 0, 64);
    float es = expf(a0.x - m) + expf(a0.y - m) + expf(a0.z - m) + expf(a0.w - m) +
               expf(a1.x - m) + expf(a1.y - m) + expf(a1.z - m) + expf(a1.w - m);
    float ss = a0.x * a0.x + a0.y * a0.y + a0.z * a0.z + a0.w * a0.w +
               a1.x * a1.x + a1.y * a1.y + a1.z * a1.z + a1.w * a1.w;
    float st = b0.x * b0.x + b0.y * b0.y + b0.z * b0.z + b0.w * b0.w +
               b1.x * b1.x + b1.y * b1.y + b1.z * b1.z + b1.w * b1.w;
#pragma unroll
    for (int off = 32; off > 0; off >>= 1) {
      es += __shfl_down(es, off, 64);
      ss += __shfl_down(ss, off, 64);
      st += __shfl_down(st, off, 64);
    }
    if (lane == 0) {
      ws[SQS_OFF + r] = ss;
      ws[SQT_OFF + r] = st;
      ws[HARD_OFF + r] = m + logf(es) - xs[lab[r]];
    }
  } else {
    int w = t >> 6, lane = t & 63;
    int g = (blockIdx.x - 96) * 4 + w;   // [0, 600)
    int tensor = (g >= UP16) ? 1 : 0;
    int uu = g - tensor * UP16;
    int ti = 0;
    while (uu >= T16 - ti) { uu -= T16 - ti; ++ti; }
    int tj = ti + uu;
    const float* F = tensor ? ft : fs;
    float* P = ws + (tensor ? PT_OFF : PS_OFF);
    int i0 = ti * 16, j0 = tj * 16;
    int r = lane & 15, q = lane >> 4;
    // A[m=lane&15][k=quad*8+j], B[k=quad*8+j][n=lane&15] (m89-verified mapping)
    const float* arow = F + (i0 + r) * C + q * 8;
    const float* brow = F + (j0 + r) * C + q * 8;
    floatx4 acc = {0.f, 0.f, 0.f, 0.f};
    float sqa = 0.f, sqb = 0.f;
#pragma unroll
    for (int ks = 0; ks < 16; ++ks) {
      float4 al = *(const float4*)(arow + ks * 32);
      float4 ah = *(const float4*)(arow + ks * 32 + 4);
      float4 bl = *(const float4*)(brow + ks * 32);
      float4 bh = *(const float4*)(brow + ks * 32 + 4);
      sqa += al.x * al.x + al.y * al.y + al.z * al.z + al.w * al.w +
             ah.x * ah.x + ah.y * ah.y + ah.z * ah.z + ah.w * ah.w;
      sqb += bl.x * bl.x + bl.y * bl.y + bl.z * bl.z + bl.w * bl.w +
             bh.x * bh.x + bh.y * bh.y + bh.z * bh.z + bh.w * bh.w;
      short8 a, b;
      a[0] = bfc(al.x); a[1] = bfc(al.y); a[2] = bfc(al.z); a[3] = bfc(al.w);
      a[4] = bfc(ah.x); a[5] = bfc(ah.y); a[6] = bfc(ah.z); a[7] = bfc(ah.w);
      b[0] = bfc(bl.x); b[1] = bfc(bl.y); b[2] = bfc(bl.z); b[3] = bfc(bl.w);
      b[4] = bfc(bh.x); b[5] = bfc(bh.y); b[6] = bfc(bh.z); b[7] = bfc(bh.w);
      acc = __builtin_amdgcn_mfma_f32_16x16x32_bf16(a, b, acc, 0, 0, 0);
    }
    // full row norms: reduce partial sums over the 4 lane-quads (r, r+16, r+32, r+48)
    sqa += __shfl_xor(sqa, 16, 64); sqa += __shfl_xor(sqa, 32, 64);
    sqb += __shfl_xor(sqb, 16, 64); sqb += __shfl_xor(sqb, 32, 64);
    // C/D layout: col = lane&15, row = quad*4 + reg
    int col = lane & 15;
    int j = j0 + col;
    float sqj = __shfl(sqb, col, 64);
    float dsum = 0.f;
#pragma unroll
    for (int reg = 0; reg < 4; ++reg) {
      int ii = q * 4 + reg;
      int i = i0 + ii;
      float sqi = __shfl(sqa, ii, 64);
      float p = acc[reg];
      P[i * B + j] = p;
      P[j * B + i] = p;   // symmetric mirror (diag tile: identical value, benign)
      float d2 = sqi + sqj - 2.f * p;
      float d = sqrtf(fmaxf(d2, 1e-12f));
      float wgt = (ti < tj) ? 2.f : ((i < j) ? 2.f : 0.f);
      dsum = fmaf(wgt, d, dsum);
    }
#pragma unroll
    for (int off = 32; off > 0; off >>= 1) dsum += __shfl_down(dsum, off, 64);
    if (lane == 0) ws[DSUM_OFF + g] = dsum;
  }
}

// K_B: angle-huber over upper-triangle 64x64 (i,j) tiles via Gram identity;
// dist-huber fused into y==0 blocks (normalizer from prior-dispatch DSUM slots).
// Pure compute: plain partial stores only.
#define BCH 12
#define ANGLE_BODY(MASKED)                                                   \
  for (int b = 0; b < BCH; ++b) {                                            \
    float uis[4], qis[4], uit[4], qit[4], ujs[4], qjs[4], ujt[4], qjt[4];    \
    float4 v;                                                                \
    v = *(const float4*)&sI[b][0][ty * 4];                                   \
    uis[0] = v.x; uis[1] = v.y; uis[2] = v.z; uis[3] = v.w;                  \
    v = *(const float4*)&sI[b][1][ty * 4];                                   \
    qis[0] = v.x; qis[1] = v.y; qis[2] = v.z; qis[3] = v.w;                  \
    v = *(const float4*)&sI[b][2][ty * 4];                                   \
    uit[0] = v.x; uit[1] = v.y; uit[2] = v.z; uit[3] = v.w;                  \
    v = *(const float4*)&sI[b][3][ty * 4];                                   \
    qit[0] = v.x; qit[1] = v.y; qit[2] = v.z; qit[3] = v.w;                  \
    v = *(const float4*)&sJ[b][0][tx * 4];                                   \
    ujs[0] = v.x; ujs[1] = v.y; ujs[2] = v.z; ujs[3] = v.w;                  \
    v = *(const float4*)&sJ[b][1][tx * 4];                                   \
    qjs[0] = v.x; qjs[1] = v.y; qjs[2] = v.z; qjs[3] = v.w;                  \
    v = *(const float4*)&sJ[b][2][tx * 4];                                   \
    ujt[0] = v.x; ujt[1] = v.y; ujt[2] = v.z; ujt[3] = v.w;                  \
    v = *(const float4*)&sJ[b][3][tx * 4];                                   \
    qjt[0] = v.x; qjt[1] = v.y; qjt[2] = v.z; qjt[3] = v.w;                  \
    _Pragma("unroll")                                                        \
    for (int r = 0; r < 4; ++r) {                                            \
      _Pragma("unroll")                                                      \
      for (int c = 0; c < 4; ++c) {                                          \
        float f1s = fmaf(uis[r], ps[r][c], -qis[r]);                         \
        float gs = fmaf(ujs[c], f1s, -(uis[r] * qjs[c]));                    \
        float f1t = fmaf(uit[r], pt[r][c], -qit[r]);                         \
        float gt = fmaf(ujt[c], f1t, -(uit[r] * qjt[c]));                    \
        float a = fabsf(gs - gt);                                            \
        if (MASKED) a = (ty * 4 + r < tx * 4 + c) ? a : 0.f;                 \
        float mm = fminf(a, 1.f);                                            \
        acc = fmaf(mm, fmaf(-0.5f, mm, a), acc);                             \
      }                                                                      \
    }                                                                        \
  }

__global__ __launch_bounds__(256, 4) void k_angle(float* __restrict__ ws) {
  const float* Ps = ws + PS_OFF;
  const float* Pt = ws + PT_OFF;
  const float* sqs = ws + SQS_OFF;
  const float* sqt = ws + SQT_OFF;
  int uu = blockIdx.x;
  int ti = 0;
  while (uu >= T64 - ti) { uu -= T64 - ti; ++ti; }
  int tj = ti + uu;
  int i0 = ti * 64, j0 = tj * 64;
  bool diag = (ti == tj);
  int b0 = blockIdx.y * BCH;
  int t = threadIdx.x;
  int ty = t >> 4, tx = t & 15;

  __shared__ float sI[BCH][4][64];  // planes: us, qs, ut, qt
  __shared__ float sJ[BCH][4][64];
  __shared__ float s4[4];

  float ps[4][4], pt[4][4];
#pragma unroll
  for (int r = 0; r < 4; ++r) {
    float4 v = *(const float4*)&Ps[(i0 + ty * 4 + r) * B + j0 + tx * 4];
    ps[r][0] = v.x; ps[r][1] = v.y; ps[r][2] = v.z; ps[r][3] = v.w;
    v = *(const float4*)&Pt[(i0 + ty * 4 + r) * B + j0 + tx * 4];
    pt[r][0] = v.x; pt[r][1] = v.y; pt[r][2] = v.z; pt[r][3] = v.w;
  }

  for (int idx = t; idx < BCH * 128; idx += 256) {
    int b = idx >> 7, p = idx & 127;
    int bb = b0 + b;
    int col = (p < 64) ? (i0 + p) : (j0 + p - 64);
    float pvs = Ps[bb * B + col];
    float pvt = Pt[bb * B + col];
    float pbbs = Ps[bb * B + bb];
    float pbbt = Pt[bb * B + bb];
    float d2s = sqs[bb] + sqs[col] - 2.f * pvs;
    float d2t = sqt[bb] + sqt[col] - 2.f * pvt;
    float us = (col == bb) ? 0.f : rsqrtf(fmaxf(d2s, 1e-24f));
    float ut = (col == bb) ? 0.f : rsqrtf(fmaxf(d2t, 1e-24f));
    float qs = us * (pvs - 0.5f * pbbs);
    float qt = ut * (pvt - 0.5f * pbbt);
    float* dst = (p < 64) ? &sI[b][0][p] : &sJ[b][0][p - 64];
    dst[0] = us; dst[64] = qs; dst[128] = ut; dst[192] = qt;
  }
  __syncthreads();

  float acc = 0.f;
  if (diag) { ANGLE_BODY(true) } else { ANGLE_BODY(false) }

  float asum = blk_sum(acc, s4, t);
  if (t == 0) ws[ANG_OFF + blockIdx.y * UP64 + blockIdx.x] = asum;

  if (blockIdx.y == 0) {  // fused dist-huber over this (i,j) tile
    float ssum = 0.f, tsum = 0.f;
    for (int i = t; i < UP16; i += 256) ssum += ws[DSUM_OFF + i];
    for (int i = t; i < UP16; i += 256) tsum += ws[DSUM_OFF + UP16 + i];
    ssum = blk_sum(ssum, s4, t);
    tsum = blk_sum(tsum, s4, t);
    float inv_ms = (float)NOFF / ssum;
    float inv_mt = (float)NOFF / tsum;
    float sqsi[4], sqti[4], sqsj[4], sqtj[4];
#pragma unroll
    for (int r = 0; r < 4; ++r) {
      sqsi[r] = sqs[i0 + ty * 4 + r];
      sqti[r] = sqt[i0 + ty * 4 + r];
      sqsj[r] = sqs[j0 + tx * 4 + r];
      sqtj[r] = sqt[j0 + tx * 4 + r];
    }
    float dacc = 0.f;
#pragma unroll
    for (int r = 0; r < 4; ++r)
#pragma unroll
      for (int c = 0; c < 4; ++c) {
        float d2s = sqsi[r] + sqsj[c] - 2.f * ps[r][c];
        float d2t = sqti[r] + sqtj[c] - 2.f * pt[r][c];
        float dsv = sqrtf(fmaxf(d2s, 1e-12f)) * inv_ms;
        float dtv = sqrtf(fmaxf(d2t, 1e-12f)) * inv_mt;
        float a = fabsf(dsv - dtv);
        if (diag) a = (ty * 4 + r < tx * 4 + c) ? a : 0.f;
        float mm = fminf(a, 1.f);
        dacc = fmaf(mm, fmaf(-0.5f, mm, a), dacc);
      }
    float dsum2 = blk_sum(dacc, s4, t);
    if (t == 0) ws[DIST_OFF + blockIdx.x] = dsum2;
  }
}

// K_C: final reduce + combine (1 block)
__global__ __launch_bounds__(256) void k_final(const float* __restrict__ ws,
                                               float* __restrict__ out) {
  __shared__ float s4[4];
  int t = threadIdx.x;
  float h = 0.f;
  for (int i = t; i < B; i += 256) h += ws[HARD_OFF + i];
  float a = 0.f;
  for (int i = t; i < NANG; i += 256) a += ws[ANG_OFF + i];
  float d = 0.f;
  for (int i = t; i < UP64; i += 256) d += ws[DIST_OFF + i];
  h = blk_sum(h, s4, t);
  a = blk_sum(a, s4, t);
  d = blk_sum(d, s4, t);
  if (t == 0)
    out[0] = h * (1.f / (float)B) + 2.f * d * (1.f / (float)NPAIR) +
             2.f * a * (1.f / 56623104.f);  // 384^3
}

extern "C" void kernel_launch(void* const* d_in, const int* in_sizes, int n_in,
                              void* d_out, int out_size, void* d_ws, size_t ws_size,
                              hipStream_t stream) {
  (void)in_sizes; (void)n_in; (void)out_size; (void)ws_size;
  const float* fs = (const float*)d_in[0];
  const float* ft = (const float*)d_in[1];
  const int* lab = (const int*)d_in[2];
  float* ws = (float*)d_ws;
  float* out = (float*)d_out;

  k_pre<<<246, 256, 0, stream>>>(fs, ft, lab, ws);       // 96 row blocks + 150 gram blocks
  k_angle<<<dim3(UP64, NBG), 256, 0, stream>>>(ws);      // 21 tiles x 32 b-groups
  k_final<<<1, 256, 0, stream>>>(ws, out);
}

// Round 6
// 81.867 us; speedup vs baseline: 1.6958x; 1.0516x over previous
//
#include <hip/hip_runtime.h>
#include <hip/hip_bf16.h>
#include <math.h>

#define B 384
#define C 512
#define NPAIR (B * B)          // 147456
#define NOFF  (B * (B - 1))    // 147072

#define T16  24   // 16x16 tiles per dim in gram
#define UP16 300  // upper-incl-diag tile count (24*25/2)
#define T64  6    // 64x64 tiles per dim in angle
#define UP64 21   // 6*7/2
#define NBG  48   // b-groups in angle (384 / BCH)
#define NANG (UP64 * NBG)  // 1008 angle blocks

// ws layout (floats). ALL cross-block data crosses a dispatch boundary as plain
// stores to distinct addresses. Zero atomics / fences / spins (R3/R4 lesson).
#define HARD_OFF 0            // 384: per-row CE
#define DSUM_OFF 384          // 600: per-gram-wave weighted d-sums
#define ANG_OFF  984          // 1008: per-angle-block huber partials
#define DIST_OFF 1992         // 21: per-(y==0)-angle-block dist-huber partials
#define SQS_OFF  2016         // 384
#define SQT_OFF  2400         // 384
#define PS_OFF   2816         // 147456 (16B-aligned)
#define PT_OFF   (PS_OFF + NPAIR)

typedef __attribute__((ext_vector_type(8))) short short8;
typedef __attribute__((ext_vector_type(4))) float floatx4;

__device__ __forceinline__ float blk_sum(float v, float* s4, int t) {
#pragma unroll
  for (int off = 32; off > 0; off >>= 1) v += __shfl_down(v, off, 64);
  if ((t & 63) == 0) s4[t >> 6] = v;
  __syncthreads();
  float r = s4[0] + s4[1] + s4[2] + s4[3];
  __syncthreads();
  return r;
}

__device__ __forceinline__ short bfc(float x) {
  __hip_bfloat16 h = __float2bfloat16(x);
  return __builtin_bit_cast(short, h);
}

// K_A: blocks [0,96) = wave-per-row CE + sq norms; blocks [96,246) = gram tiles
// with fused weighted-distance-sum epilogue (row norms recomputed in-register).
__global__ __launch_bounds__(256, 4) void k_pre(const float* __restrict__ fs,
                                                const float* __restrict__ ft,
                                                const int* __restrict__ lab,
                                                float* __restrict__ ws) {
  int t = threadIdx.x;
  if (blockIdx.x < 96) {
    int wv = t >> 6, lane = t & 63;
    int r = blockIdx.x * 4 + wv;
    const float* xs = fs + r * C;
    const float* xt = ft + r * C;
    float4 a0 = *(const float4*)&xs[lane * 8];
    float4 a1 = *(const float4*)&xs[lane * 8 + 4];
    float4 b0 = *(const float4*)&xt[lane * 8];
    float4 b1 = *(const float4*)&xt[lane * 8 + 4];
    float m = fmaxf(fmaxf(fmaxf(a0.x, a0.y), fmaxf(a0.z, a0.w)),
                    fmaxf(fmaxf(a1.x, a1.y), fmaxf(a1.z, a1.w)));
#pragma unroll
    for (int off = 32; off > 0; off >>= 1) m = fmaxf(m, __shfl_down(m, off, 64));
    m = __shfl(m, 0, 64);
    float es = expf(a0.x - m) + expf(a0.y - m) + expf(a0.z - m) + expf(a0.w - m) +
               expf(a1.x - m) + expf(a1.y - m) + expf(a1.z - m) + expf(a1.w - m);
    float ss = a0.x * a0.x + a0.y * a0.y + a0.z * a0.z + a0.w * a0.w +
               a1.x * a1.x + a1.y * a1.y + a1.z * a1.z + a1.w * a1.w;
    float st = b0.x * b0.x + b0.y * b0.y + b0.z * b0.z + b0.w * b0.w +
               b1.x * b1.x + b1.y * b1.y + b1.z * b1.z + b1.w * b1.w;
#pragma unroll
    for (int off = 32; off > 0; off >>= 1) {
      es += __shfl_down(es, off, 64);
      ss += __shfl_down(ss, off, 64);
      st += __shfl_down(st, off, 64);
    }
    if (lane == 0) {
      ws[SQS_OFF + r] = ss;
      ws[SQT_OFF + r] = st;
      ws[HARD_OFF + r] = m + logf(es) - xs[lab[r]];
    }
  } else {
    int w = t >> 6, lane = t & 63;
    int g = (blockIdx.x - 96) * 4 + w;   // [0, 600)
    int tensor = (g >= UP16) ? 1 : 0;
    int uu = g - tensor * UP16;
    int ti = 0;
    while (uu >= T16 - ti) { uu -= T16 - ti; ++ti; }
    int tj = ti + uu;
    const float* F = tensor ? ft : fs;
    float* P = ws + (tensor ? PT_OFF : PS_OFF);
    int i0 = ti * 16, j0 = tj * 16;
    int r = lane & 15, q = lane >> 4;
    // A[m=lane&15][k=quad*8+j], B[k=quad*8+j][n=lane&15] (m89-verified mapping)
    const float* arow = F + (i0 + r) * C + q * 8;
    const float* brow = F + (j0 + r) * C + q * 8;
    floatx4 acc = {0.f, 0.f, 0.f, 0.f};
    float sqa = 0.f, sqb = 0.f;
#pragma unroll
    for (int ks = 0; ks < 16; ++ks) {
      float4 al = *(const float4*)(arow + ks * 32);
      float4 ah = *(const float4*)(arow + ks * 32 + 4);
      float4 bl = *(const float4*)(brow + ks * 32);
      float4 bh = *(const float4*)(brow + ks * 32 + 4);
      sqa += al.x * al.x + al.y * al.y + al.z * al.z + al.w * al.w +
             ah.x * ah.x + ah.y * ah.y + ah.z * ah.z + ah.w * ah.w;
      sqb += bl.x * bl.x + bl.y * bl.y + bl.z * bl.z + bl.w * bl.w +
             bh.x * bh.x + bh.y * bh.y + bh.z * bh.z + bh.w * bh.w;
      short8 a, b;
      a[0] = bfc(al.x); a[1] = bfc(al.y); a[2] = bfc(al.z); a[3] = bfc(al.w);
      a[4] = bfc(ah.x); a[5] = bfc(ah.y); a[6] = bfc(ah.z); a[7] = bfc(ah.w);
      b[0] = bfc(bl.x); b[1] = bfc(bl.y); b[2] = bfc(bl.z); b[3] = bfc(bl.w);
      b[4] = bfc(bh.x); b[5] = bfc(bh.y); b[6] = bfc(bh.z); b[7] = bfc(bh.w);
      acc = __builtin_amdgcn_mfma_f32_16x16x32_bf16(a, b, acc, 0, 0, 0);
    }
    // full row norms: reduce partial sums over the 4 lane-quads
    sqa += __shfl_xor(sqa, 16, 64); sqa += __shfl_xor(sqa, 32, 64);
    sqb += __shfl_xor(sqb, 16, 64); sqb += __shfl_xor(sqb, 32, 64);
    // C/D layout: col = lane&15, row = quad*4 + reg
    int col = lane & 15;
    int j = j0 + col;
    float sqj = __shfl(sqb, col, 64);
    float dsum = 0.f;
#pragma unroll
    for (int reg = 0; reg < 4; ++reg) {
      int ii = q * 4 + reg;
      int i = i0 + ii;
      float sqi = __shfl(sqa, ii, 64);
      float p = acc[reg];
      P[i * B + j] = p;
      P[j * B + i] = p;   // symmetric mirror (diag tile: identical value, benign)
      float d2 = sqi + sqj - 2.f * p;
      float d = sqrtf(fmaxf(d2, 1e-12f));
      float wgt = (ti < tj) ? 2.f : ((i < j) ? 2.f : 0.f);
      dsum = fmaf(wgt, d, dsum);
    }
#pragma unroll
    for (int off = 32; off > 0; off >>= 1) dsum += __shfl_down(dsum, off, 64);
    if (lane == 0) ws[DSUM_OFF + g] = dsum;
  }
}

// K_B: angle-huber over upper-triangle 64x64 (i,j) tiles via Gram identity.
// LDS: float4-packed (u_s, q_s, u_t, q_t) per (b, col); body = fully-unrolled
// b-loop with register double-buffer (prefetch b+1 fragments during b's triples).
#define BCH 8
__global__ __launch_bounds__(256, 3) void k_angle(float* __restrict__ ws) {
  const float* Ps = ws + PS_OFF;
  const float* Pt = ws + PT_OFF;
  const float* sqs = ws + SQS_OFF;
  const float* sqt = ws + SQT_OFF;
  int uu = blockIdx.x;
  int ti = 0;
  while (uu >= T64 - ti) { uu -= T64 - ti; ++ti; }
  int tj = ti + uu;
  int i0 = ti * 64, j0 = tj * 64;
  bool diag = (ti == tj);
  int b0 = blockIdx.y * BCH;
  int t = threadIdx.x;
  int ty = t >> 4, tx = t & 15;

  __shared__ float4 sI4[BCH][64];  // (us,qs,ut,qt) per (b, i-col)
  __shared__ float4 sJ4[BCH][64];
  __shared__ float s4[4];

  float ps[4][4], pt[4][4];
#pragma unroll
  for (int r = 0; r < 4; ++r) {
    float4 v = *(const float4*)&Ps[(i0 + ty * 4 + r) * B + j0 + tx * 4];
    ps[r][0] = v.x; ps[r][1] = v.y; ps[r][2] = v.z; ps[r][3] = v.w;
    v = *(const float4*)&Pt[(i0 + ty * 4 + r) * B + j0 + tx * 4];
    pt[r][0] = v.x; pt[r][1] = v.y; pt[r][2] = v.z; pt[r][3] = v.w;
  }

  for (int idx = t; idx < BCH * 128; idx += 256) {
    int b = idx >> 7, p = idx & 127;
    int bb = b0 + b;
    int col = (p < 64) ? (i0 + p) : (j0 + p - 64);
    float pvs = Ps[bb * B + col];
    float pvt = Pt[bb * B + col];
    float pbbs = Ps[bb * B + bb];
    float pbbt = Pt[bb * B + bb];
    float d2s = sqs[bb] + sqs[col] - 2.f * pvs;
    float d2t = sqt[bb] + sqt[col] - 2.f * pvt;
    float us = (col == bb) ? 0.f : rsqrtf(fmaxf(d2s, 1e-24f));
    float ut = (col == bb) ? 0.f : rsqrtf(fmaxf(d2t, 1e-24f));
    float4 pk;
    pk.x = us;
    pk.y = us * (pvs - 0.5f * pbbs);
    pk.z = ut;
    pk.w = ut * (pvt - 0.5f * pbbt);
    if (p < 64) sI4[b][p] = pk; else sJ4[b][p - 64] = pk;
  }
  __syncthreads();

  float acc = 0.f;
  // register double-buffer over b: preload b+1's fragments during b's triples
  float4 vi[4], vj[4], nvi[4], nvj[4];
#pragma unroll
  for (int r = 0; r < 4; ++r) {
    vi[r] = sI4[0][ty * 4 + r];
    vj[r] = sJ4[0][tx * 4 + r];
  }
#pragma unroll
  for (int b = 0; b < BCH; ++b) {
    if (b + 1 < BCH) {
#pragma unroll
      for (int r = 0; r < 4; ++r) {
        nvi[r] = sI4[b + 1][ty * 4 + r];
        nvj[r] = sJ4[b + 1][tx * 4 + r];
      }
    }
#pragma unroll
    for (int r = 0; r < 4; ++r) {
#pragma unroll
      for (int c = 0; c < 4; ++c) {
        float f1s = fmaf(vi[r].x, ps[r][c], -vi[r].y);
        float gs = fmaf(vj[c].x, f1s, -(vi[r].x * vj[c].y));
        float f1t = fmaf(vi[r].z, pt[r][c], -vi[r].w);
        float gt = fmaf(vj[c].z, f1t, -(vi[r].z * vj[c].w));
        float a = fabsf(gs - gt);
        if (diag) a = (ty * 4 + r < tx * 4 + c) ? a : 0.f;
        float mm = fminf(a, 1.f);
        acc = fmaf(mm, fmaf(-0.5f, mm, a), acc);
      }
    }
#pragma unroll
    for (int r = 0; r < 4; ++r) { vi[r] = nvi[r]; vj[r] = nvj[r]; }
  }

  float asum = blk_sum(acc, s4, t);
  if (t == 0) ws[ANG_OFF + blockIdx.y * UP64 + blockIdx.x] = asum;

  if (blockIdx.y == 0) {  // fused dist-huber over this (i,j) tile
    float ssum = 0.f, tsum = 0.f;
    for (int i = t; i < UP16; i += 256) ssum += ws[DSUM_OFF + i];
    for (int i = t; i < UP16; i += 256) tsum += ws[DSUM_OFF + UP16 + i];
    ssum = blk_sum(ssum, s4, t);
    tsum = blk_sum(tsum, s4, t);
    float inv_ms = (float)NOFF / ssum;
    float inv_mt = (float)NOFF / tsum;
    float sqsi[4], sqti[4], sqsj[4], sqtj[4];
#pragma unroll
    for (int r = 0; r < 4; ++r) {
      sqsi[r] = sqs[i0 + ty * 4 + r];
      sqti[r] = sqt[i0 + ty * 4 + r];
      sqsj[r] = sqs[j0 + tx * 4 + r];
      sqtj[r] = sqt[j0 + tx * 4 + r];
    }
    float dacc = 0.f;
#pragma unroll
    for (int r = 0; r < 4; ++r)
#pragma unroll
      for (int c = 0; c < 4; ++c) {
        float d2s = sqsi[r] + sqsj[c] - 2.f * ps[r][c];
        float d2t = sqti[r] + sqtj[c] - 2.f * pt[r][c];
        float dsv = sqrtf(fmaxf(d2s, 1e-12f)) * inv_ms;
        float dtv = sqrtf(fmaxf(d2t, 1e-12f)) * inv_mt;
        float a = fabsf(dsv - dtv);
        if (diag) a = (ty * 4 + r < tx * 4 + c) ? a : 0.f;
        float mm = fminf(a, 1.f);
        dacc = fmaf(mm, fmaf(-0.5f, mm, a), dacc);
      }
    float dsum2 = blk_sum(dacc, s4, t);
    if (t == 0) ws[DIST_OFF + blockIdx.x] = dsum2;
  }
}

// K_C: final reduce + combine (1 block)
__global__ __launch_bounds__(256) void k_final(const float* __restrict__ ws,
                                               float* __restrict__ out) {
  __shared__ float s4[4];
  int t = threadIdx.x;
  float h = 0.f;
  for (int i = t; i < B; i += 256) h += ws[HARD_OFF + i];
  float a = 0.f;
  for (int i = t; i < NANG; i += 256) a += ws[ANG_OFF + i];
  float d = 0.f;
  for (int i = t; i < UP64; i += 256) d += ws[DIST_OFF + i];
  h = blk_sum(h, s4, t);
  a = blk_sum(a, s4, t);
  d = blk_sum(d, s4, t);
  if (t == 0)
    out[0] = h * (1.f / (float)B) + 2.f * d * (1.f / (float)NPAIR) +
             2.f * a * (1.f / 56623104.f);  // 384^3
}

extern "C" void kernel_launch(void* const* d_in, const int* in_sizes, int n_in,
                              void* d_out, int out_size, void* d_ws, size_t ws_size,
                              hipStream_t stream) {
  (void)in_sizes; (void)n_in; (void)out_size; (void)ws_size;
  const float* fs = (const float*)d_in[0];
  const float* ft = (const float*)d_in[1];
  const int* lab = (const int*)d_in[2];
  float* ws = (float*)d_ws;
  float* out = (float*)d_out;

  k_pre<<<246, 256, 0, stream>>>(fs, ft, lab, ws);       // 96 row blocks + 150 gram blocks
  k_angle<<<dim3(UP64, NBG), 256, 0, stream>>>(ws);      // 21 tiles x 48 b-groups
  k_final<<<1, 256, 0, stream>>>(ws, out);
}